// Round 2
// baseline (3660.744 us; speedup 1.0000x reference)
//
#include <hip/hip_runtime.h>
#include <math.h>

#define BB 8
#define IMGS 224
#define PSZ 16
#define CC 96
#define DEPTH 12
#define NCLS 43
#define HH 14
#define WW 14
#define LL 196
#define DD 192
#define NSTATE 16
#define RRANK 6
#define KDIR 4
#define DBLC 38     // R + 2N = 6 + 32 (logical outputs of x_proj)
#define NSEG 16     // segments per chain
#define PTOK 4      // tokens per patch-embed vblock
// per-(b,k) dbl region: dtT[6][200] + B[196][16] + Ct[16][200]
#define TSTR 200    // row stride for dtT / Ct
#define OFF_B 1200
#define OFF_C 4336
#define DBKSZ 7552  // 1200 + 3136 + 3200 + 16 pad
#define XT 14       // tokens per x_proj tile (56 vblocks per b)
#define XPAD 196    // x-tile row stride (mult of 4 => float4-aligned LDS reads)
#define GT 4        // tokens per gateproj vblock (49 per b)
#define YSTRIDE (BB * DD * LL)  // per-direction ysum plane

__device__ __forceinline__ float wave_sum(float v) {
#pragma unroll
  for (int m = 32; m; m >>= 1) v += __shfl_xor(v, m, 64);
  return v;
}

__device__ __forceinline__ float silu_f(float x) {
  return x / (1.f + __expf(-x));
}

// -------- shared-memory union: one 40 KB block reused by every phase --------
union SMem {
  struct { float w[DBLC * DD]; float x[XT * XPAD]; } xp;  // 40160 B (max)
  struct {
    float h[2][NSTATE][LL + 1];
    float dt[2][LL]; float u[2][LL]; float xv[2][LL]; float cumdt[2][LL];
    float hin[2][NSEG][NSTATE]; float hend[2][NSEG][NSTATE]; float cum[2][NSEG][NSTATE];
    float segsum[2][NSEG]; float A[2][NSTATE]; float y[2][LL];
    unsigned short src[LL];
  } sc;                                                    // ~39.9 KB
  struct { float g[GT][DD]; float t[GT][CC]; float x[GT][CC]; float p[2][GT][CC]; } gp;
  struct { float x[PTOK][768]; } pt;
  struct { float x[CC]; } ln;
  struct { float part[2][CC]; float pool[CC]; } hd;
};

// -------- per-batch barrier: 96-128 blocks arrive on counter[b]; monotonic epochs --------
__device__ __forceinline__ void bsync(unsigned* bar, int b, int gpb, unsigned epoch) {
  __syncthreads();
  if (threadIdx.x == 0) {
    __threadfence();                       // release: make this block's writes visible device-wide
    atomicAdd(bar + b * 32, 1u);           // device-scope by default
    unsigned target = epoch * (unsigned)gpb;
    while (__hip_atomic_load(bar + b * 32, __ATOMIC_ACQUIRE, __HIP_MEMORY_SCOPE_AGENT) < target)
      __builtin_amdgcn_s_sleep(1);
    __threadfence();                       // acquire side
  }
  __syncthreads();
}

// ---------------- patch embed phase: 4 tokens/vblock, 256 threads ----------------
__device__ void phase_patch(SMem& sm, int tok0, const float* __restrict__ x,
                            const float* __restrict__ pw, const float* __restrict__ pb,
                            const float* __restrict__ pos, float* __restrict__ t) {
  int tid = threadIdx.x;
  for (int tk = 0; tk < PTOK; tk++) {
    int tok = tok0 + tk;
    int b = tok / LL, l = tok % LL;
    int ph = l / WW, pwc = l % WW;
    for (int e = tid; e < 768; e += 256) {
      int ci = e >> 8, kh = (e >> 4) & 15, kw = e & 15;
      sm.pt.x[tk][e] = x[((size_t)(b * 3 + ci) * IMGS + ph * PSZ + kh) * IMGS + pwc * PSZ + kw];
    }
  }
  __syncthreads();
  if (tid < CC) {
    int c = tid;
    float a0 = pb[c], a1 = a0, a2 = a0, a3 = a0;
    const float* wr = pw + (size_t)c * 768;
    for (int e = 0; e < 768; e++) {
      float wv = wr[e];
      a0 += sm.pt.x[0][e] * wv;
      a1 += sm.pt.x[1][e] * wv;
      a2 += sm.pt.x[2][e] * wv;
      a3 += sm.pt.x[3][e] * wv;
    }
    float acc[4] = {a0, a1, a2, a3};
    for (int tk = 0; tk < PTOK; tk++) {
      int tok = tok0 + tk;
      t[(size_t)tok * CC + c] = acc[tk] + pos[(tok % LL) * CC + c];
    }
  }
}

// ---------------- LN(96) + in_proj phase (layer 0), 1 token/vblock, 256 threads ----------------
__device__ void phase_lnproj(SMem& sm, int tok, const float* __restrict__ t,
                             const float* __restrict__ w, const float* __restrict__ bias,
                             const float* __restrict__ ipw, float* __restrict__ xa,
                             float* __restrict__ z) {
  int tid = threadIdx.x;
  if (tid < 64) {
    const float* p = t + (size_t)tok * CC;
    float v0 = p[tid];
    float v1 = (tid < CC - 64) ? p[tid + 64] : 0.f;
    float mu = wave_sum(v0 + v1) * (1.f / CC);
    float d0 = v0 - mu;
    float d1 = (tid < CC - 64) ? (v1 - mu) : 0.f;
    float var = wave_sum(d0 * d0 + d1 * d1) * (1.f / CC);
    float rs = rsqrtf(var + 1e-6f);
    sm.ln.x[tid] = d0 * rs * w[tid] + bias[tid];
    if (tid < CC - 64) sm.ln.x[tid + 64] = d1 * rs * w[tid + 64] + bias[tid + 64];
  }
  __syncthreads();
  float a0 = 0.f, a1 = 0.f;
  bool two = tid < (2 * DD - 256);  // 128: waves 0,1 -> uniform
  for (int c = 0; c < CC; c++) {
    float xv = sm.ln.x[c];
    a0 += xv * ipw[(size_t)c * (2 * DD) + tid];
    if (two) a1 += xv * ipw[(size_t)c * (2 * DD) + tid + 256];
  }
  if (tid < DD) xa[(size_t)tok * DD + tid] = a0;
  else z[(size_t)tok * DD + (tid - DD)] = a0;
  if (two) z[(size_t)tok * DD + (tid + 256 - DD)] = a1;
}

// ---------------- x_proj phase (conv fused), one (k, lt) tile per vblock ----------------
__device__ void phase_xproj(SMem& sm, int b, int k, int lt,
                            const float* __restrict__ xa, const float* __restrict__ cw,
                            const float* __restrict__ cbp, const float* __restrict__ xpw,
                            float* __restrict__ xcT, float* __restrict__ dbl) {
  int tid = threadIdx.x;
  int l0 = lt * XT;

  const float4* wsrc = (const float4*)(xpw + (size_t)k * DBLC * DD);
  float4* wdst = (float4*)sm.xp.w;
  for (int idx = tid; idx < (DBLC * DD) / 4; idx += 256) wdst[idx] = wsrc[idx];

  for (int idx = tid; idx < XT * (DD / 4); idx += 256) {
    int i = idx / (DD / 4);
    int d = (idx % (DD / 4)) * 4;
    int l = l0 + i;
    int lr = (k >= 2) ? (LL - 1 - l) : l;
    int src = (k & 1) ? ((lr % HH) * WW + lr / HH) : lr;
    int h = src / WW, w = src % WW;
    const float4 bv = *(const float4*)(cbp + d);
    float a0 = bv.x, a1 = bv.y, a2 = bv.z, a3 = bv.w;
    if (h >= 1 && h < HH - 1 && w >= 1 && w < WW - 1) {
#pragma unroll
      for (int kh = 0; kh < 3; kh++) {
#pragma unroll
        for (int kw = 0; kw < 3; kw++) {
          const float4 v = *(const float4*)(
              xa + ((size_t)(b * LL + (h + kh - 1) * WW + (w + kw - 1))) * DD + d);
          int wo = kh * 3 + kw;
          a0 += v.x * cw[(d + 0) * 9 + wo];
          a1 += v.y * cw[(d + 1) * 9 + wo];
          a2 += v.z * cw[(d + 2) * 9 + wo];
          a3 += v.w * cw[(d + 3) * 9 + wo];
        }
      }
    } else {
      for (int kh = 0; kh < 3; kh++) {
        int hh = h + kh - 1;
        if (hh < 0 || hh >= HH) continue;
        for (int kw = 0; kw < 3; kw++) {
          int ww = w + kw - 1;
          if (ww < 0 || ww >= WW) continue;
          const float4 v = *(const float4*)(xa + ((size_t)(b * LL + hh * WW + ww)) * DD + d);
          int wo = kh * 3 + kw;
          a0 += v.x * cw[(d + 0) * 9 + wo];
          a1 += v.y * cw[(d + 1) * 9 + wo];
          a2 += v.z * cw[(d + 2) * 9 + wo];
          a3 += v.w * cw[(d + 3) * 9 + wo];
        }
      }
    }
    float4 r = make_float4(silu_f(a0), silu_f(a1), silu_f(a2), silu_f(a3));
    *(float4*)(sm.xp.x + i * XPAD + d) = r;
    if (k == 0) *(float4*)(xcT + ((size_t)(b * LL) + src) * DD + d) = r;  // src==l for k==0
  }
  __syncthreads();

  int li = tid & 15;
  int cbi = tid >> 4;
  if (li >= XT) return;
  int l = l0 + li;
  float* base = dbl + (size_t)(b * KDIR + k) * DBKSZ;
  const float4* xr = (const float4*)(sm.xp.x + li * XPAD);
  const float4* w0 = (const float4*)(sm.xp.w + cbi * DD);
  const float4* w1 = (const float4*)(sm.xp.w + (cbi + 16) * DD);
  bool has2 = (cbi < DBLC - 32);
  const float4* w2 = has2 ? (const float4*)(sm.xp.w + (cbi + 32) * DD) : w0;
  float a0 = 0.f, a1 = 0.f, a2 = 0.f;
#pragma unroll 8
  for (int q = 0; q < DD / 4; q++) {
    float4 a = xr[q];
    float4 v0 = w0[q], v1 = w1[q], v2 = w2[q];
    a0 += a.x * v0.x + a.y * v0.y + a.z * v0.z + a.w * v0.w;
    a1 += a.x * v1.x + a.y * v1.y + a.z * v1.z + a.w * v1.w;
    a2 += a.x * v2.x + a.y * v2.y + a.z * v2.z + a.w * v2.w;
  }
  {
    int c = cbi;
    if (c < RRANK) base[c * TSTR + l] = a0;
    else base[OFF_B + l * NSTATE + (c - RRANK)] = a0;
  }
  {
    int c = cbi + 16;
    if (c < RRANK + NSTATE) base[OFF_B + l * NSTATE + (c - RRANK)] = a1;
    else base[OFF_C + (c - RRANK - NSTATE) * TSTR + l] = a1;
  }
  if (has2) {
    int c = cbi + 32;
    base[OFF_C + (c - RRANK - NSTATE) * TSTR + l] = a2;
  }
}

// ---------------- selective scan phase: one (dp, k) per vblock ----------------
__device__ void phase_scan(SMem& sm, int b, int dp, int k,
                           const float* __restrict__ xcT, const float* __restrict__ dbl,
                           const float* __restrict__ dtw, const float* __restrict__ dtb,
                           const float* __restrict__ alog, const float* __restrict__ dsv,
                           float* __restrict__ ysum) {
  int tid = threadIdx.x;
  int s = tid >> 4;
  int n = tid & 15;
  int d0 = dp * 2;

  int len = (s < 4) ? 13 : 12;
  int l0 = s * 12 + ((s < 4) ? s : 4);

  float A0 = -__expf(alog[((size_t)k * DD + d0) * NSTATE + n]);
  float A1 = -__expf(alog[((size_t)k * DD + d0 + 1) * NSTATE + n]);
  float Dsc0 = dsv[k * DD + d0];
  float Dsc1 = dsv[k * DD + d0 + 1];
  const float* blp = dbl + (size_t)(b * KDIR + k) * DBKSZ;
  if (tid < NSTATE) { sm.sc.A[0][tid] = A0; sm.sc.A[1][tid] = A1; }

  if (tid < LL) {
    int l = tid;
    float r[RRANK];
#pragma unroll
    for (int rr = 0; rr < RRANK; rr++) r[rr] = blp[rr * TSTR + l];
    const float* wp0 = dtw + ((size_t)k * DD + d0) * RRANK;
    const float* wp1 = wp0 + RRANK;
    float m0 = dtb[k * DD + d0], m1 = dtb[k * DD + d0 + 1];
#pragma unroll
    for (int rr = 0; rr < RRANK; rr++) { m0 += r[rr] * wp0[rr]; m1 += r[rr] * wp1[rr]; }
    float dt0 = (m0 > 20.f) ? m0 : __logf(1.f + __expf(m0));
    float dt1 = (m1 > 20.f) ? m1 : __logf(1.f + __expf(m1));
    int lr = (k >= 2) ? (LL - 1 - l) : l;
    int src = (k & 1) ? ((lr % HH) * WW + lr / HH) : lr;
    float2 xv = *(const float2*)(xcT + ((size_t)b * LL + src) * DD + d0);
    sm.sc.dt[0][l] = dt0; sm.sc.dt[1][l] = dt1;
    sm.sc.u[0][l] = dt0 * xv.x; sm.sc.u[1][l] = dt1 * xv.y;
    sm.sc.xv[0][l] = xv.x; sm.sc.xv[1][l] = xv.y;
    sm.sc.src[l] = (unsigned short)src;
  }
  __syncthreads();

  if (tid < LL) {
    int l = tid;
    int myseg = (l < 52) ? (l / 13) : (4 + (l - 52) / 12);
    int sl0 = myseg * 12 + ((myseg < 4) ? myseg : 4);
    float a0 = 0.f, a1 = 0.f;
    for (int j = sl0; j <= l; j++) { a0 += sm.sc.dt[0][j]; a1 += sm.sc.dt[1][j]; }
    sm.sc.cumdt[0][l] = a0; sm.sc.cumdt[1][l] = a1;
    int slen = (myseg < 4) ? 13 : 12;
    if (l == sl0 + slen - 1) { sm.sc.segsum[0][myseg] = a0; sm.sc.segsum[1][myseg] = a1; }
  }
  __syncthreads();

  float Breg[13];
#pragma unroll
  for (int i = 0; i < 13; i++) {
    int li = (i < len) ? (l0 + i) : l0;
    Breg[i] = blp[OFF_B + li * NSTATE + n];
  }
  float h0 = 0.f, h1 = 0.f;
#pragma unroll
  for (int i = 0; i < 13; i++) {
    if (i < len) {
      int l = l0 + i;
      float a0 = __expf(sm.sc.dt[0][l] * A0);
      float a1 = __expf(sm.sc.dt[1][l] * A1);
      h0 = h0 * a0 + sm.sc.u[0][l] * Breg[i];
      h1 = h1 * a1 + sm.sc.u[1][l] * Breg[i];
      sm.sc.h[0][n][l] = h0;
      sm.sc.h[1][n][l] = h1;
    }
  }
  sm.sc.hend[0][s][n] = h0; sm.sc.hend[1][s][n] = h1;
  sm.sc.cum[0][s][n] = __expf(A0 * sm.sc.segsum[0][s]);
  sm.sc.cum[1][s][n] = __expf(A1 * sm.sc.segsum[1][s]);
  __syncthreads();

  {
    float hh0 = 0.f, hh1 = 0.f;
    for (int ss = 0; ss < s; ss++) {
      hh0 = sm.sc.cum[0][ss][n] * hh0 + sm.sc.hend[0][ss][n];
      hh1 = sm.sc.cum[1][ss][n] * hh1 + sm.sc.hend[1][ss][n];
    }
    sm.sc.hin[0][s][n] = hh0; sm.sc.hin[1][s][n] = hh1;
  }
  __syncthreads();

  if (tid < LL) {
    int l = tid;
    int myseg = (l < 52) ? (l / 13) : (4 + (l - 52) / 12);
    float cd0 = sm.sc.cumdt[0][l], cd1 = sm.sc.cumdt[1][l];
    const float* q = blp + OFF_C + l;
    float y0 = 0.f, y1 = 0.f;
#pragma unroll
    for (int nn = 0; nn < NSTATE; nn++) {
      float Cv = q[nn * TSTR];
      float hf0 = sm.sc.h[0][nn][l] + __expf(sm.sc.A[0][nn] * cd0) * sm.sc.hin[0][myseg][nn];
      float hf1 = sm.sc.h[1][nn][l] + __expf(sm.sc.A[1][nn] * cd1) * sm.sc.hin[1][myseg][nn];
      y0 += hf0 * Cv;
      y1 += hf1 * Cv;
    }
    y0 += Dsc0 * sm.sc.xv[0][l];
    y1 += Dsc1 * sm.sc.xv[1][l];
    int src = sm.sc.src[l];
    sm.sc.y[0][src] = y0;
    sm.sc.y[1][src] = y1;
  }
  __syncthreads();
  if (tid < LL) {
    size_t base = (size_t)k * YSTRIDE + ((size_t)b * DD + d0) * LL;
    ysum[base + tid] = sm.sc.y[0][tid];
    ysum[base + LL + tid] = sm.sc.y[1][tid];
  }
}

// ---------------- gate+proj phase: 4 tokens/vblock, 256 threads ----------------
__device__ void phase_gateproj(SMem& sm, int b, int l0, const float* __restrict__ ys,
                               const float* __restrict__ onw, const float* __restrict__ onb,
                               const float* __restrict__ z, const float* __restrict__ opw,
                               float* __restrict__ t,
                               const float* __restrict__ nlw, const float* __restrict__ nlb,
                               const float* __restrict__ ipw,
                               float* __restrict__ xa, float* __restrict__ zout, int mode) {
  int tid = threadIdx.x;
  int tok0 = b * LL + l0;

  // stage 1a: per-d float4 row loads, sum 4 direction planes, transpose
  if (tid < DD) {
    size_t base = ((size_t)b * DD + tid) * LL + l0;
    float4 v0 = *(const float4*)(ys + base);
    float4 v1 = *(const float4*)(ys + (size_t)YSTRIDE + base);
    float4 v2 = *(const float4*)(ys + 2 * (size_t)YSTRIDE + base);
    float4 v3 = *(const float4*)(ys + 3 * (size_t)YSTRIDE + base);
    sm.gp.g[0][tid] = v0.x + v1.x + v2.x + v3.x;
    sm.gp.g[1][tid] = v0.y + v1.y + v2.y + v3.y;
    sm.gp.g[2][tid] = v0.z + v1.z + v2.z + v3.z;
    sm.gp.g[3][tid] = v0.w + v1.w + v2.w + v3.w;
  }
  __syncthreads();

  // stage 1b: per-wave LN(192)+silu-gate; wave w = token w (4 waves exactly)
  {
    int w = tid >> 6;
    int lane = tid & 63;
    int tok = tok0 + w;
    float v0 = sm.gp.g[w][lane];
    float v1 = sm.gp.g[w][lane + 64];
    float v2 = sm.gp.g[w][lane + 128];
    float mu = wave_sum(v0 + v1 + v2) * (1.f / DD);
    float d0 = v0 - mu, d1 = v1 - mu, d2 = v2 - mu;
    float var = wave_sum(d0 * d0 + d1 * d1 + d2 * d2) * (1.f / DD);
    float rs = rsqrtf(var + 1e-6f);
    const float* zp = z + (size_t)tok * DD;
    sm.gp.g[w][lane]       = (d0 * rs * onw[lane] + onb[lane]) * silu_f(zp[lane]);
    sm.gp.g[w][lane + 64]  = (d1 * rs * onw[lane + 64] + onb[lane + 64]) * silu_f(zp[lane + 64]);
    sm.gp.g[w][lane + 128] = (d2 * rs * onw[lane + 128] + onb[lane + 128]) * silu_f(zp[lane + 128]);
  }
  __syncthreads();

  // stage 2: out_proj partials, 2 parts x 96 d each, weights read once for 4 tokens
  if (tid < 2 * CC) {
    int c = tid % CC;
    int part = tid / CC;
    int dlo = part * 96;
    float a0 = 0.f, a1 = 0.f, a2 = 0.f, a3 = 0.f;
#pragma unroll 8
    for (int j = 0; j < 96; j++) {
      float wv = opw[(size_t)(dlo + j) * CC + c];
      a0 += sm.gp.g[0][dlo + j] * wv;
      a1 += sm.gp.g[1][dlo + j] * wv;
      a2 += sm.gp.g[2][dlo + j] * wv;
      a3 += sm.gp.g[3][dlo + j] * wv;
    }
    sm.gp.p[part][0][c] = a0;
    sm.gp.p[part][1][c] = a1;
    sm.gp.p[part][2][c] = a2;
    sm.gp.p[part][3][c] = a3;
  }
  __syncthreads();
  // residual + t update
  for (int idx = tid; idx < GT * CC; idx += 256) {
    int tk = idx / CC, c = idx % CC;
    float tn = t[(size_t)(tok0 + tk) * CC + c] + sm.gp.p[0][tk][c] + sm.gp.p[1][tk][c];
    t[(size_t)(tok0 + tk) * CC + c] = tn;
    sm.gp.t[tk][c] = tn;
  }
  __syncthreads();

  // stage 3: LN(96) per wave with nlw/nlb
  {
    int w = tid >> 6;
    int lane = tid & 63;
    float v0 = sm.gp.t[w][lane];
    float v1 = (lane < CC - 64) ? sm.gp.t[w][lane + 64] : 0.f;
    float mu2 = wave_sum(v0 + v1) * (1.f / CC);
    float d0 = v0 - mu2;
    float d1 = (lane < CC - 64) ? (v1 - mu2) : 0.f;
    float var2 = wave_sum(d0 * d0 + d1 * d1) * (1.f / CC);
    float rs2 = rsqrtf(var2 + 1e-6f);
    sm.gp.x[w][lane] = d0 * rs2 * nlw[lane] + nlb[lane];
    if (lane < CC - 64) sm.gp.x[w][lane + 64] = d1 * rs2 * nlw[lane + 64] + nlb[lane + 64];
  }
  __syncthreads();

  if (mode == 2) {
    for (int idx = tid; idx < GT * CC; idx += 256) {
      int tk = idx / CC, c = idx % CC;
      xa[(size_t)(tok0 + tk) * CC + c] = sm.gp.x[tk][c] * (1.f / LL);
    }
    return;
  }

  // stage 4: next layer's in_proj; each thread handles j=tid and (tid<128) j2=tid+256
  {
    bool two = tid < (2 * DD - 256);  // 128: waves 0,1 -> uniform
    float b0 = 0.f, b1 = 0.f, b2 = 0.f, b3 = 0.f;
    float c0 = 0.f, c1 = 0.f, c2 = 0.f, c3 = 0.f;
    for (int c = 0; c < CC; c++) {
      float x0 = sm.gp.x[0][c], x1 = sm.gp.x[1][c], x2 = sm.gp.x[2][c], x3 = sm.gp.x[3][c];
      float wv = ipw[(size_t)c * (2 * DD) + tid];
      b0 += x0 * wv; b1 += x1 * wv; b2 += x2 * wv; b3 += x3 * wv;
      if (two) {
        float wv2 = ipw[(size_t)c * (2 * DD) + tid + 256];
        c0 += x0 * wv2; c1 += x1 * wv2; c2 += x2 * wv2; c3 += x3 * wv2;
      }
    }
    float accb[GT] = {b0, b1, b2, b3};
    float accc[GT] = {c0, c1, c2, c3};
#pragma unroll
    for (int tk = 0; tk < GT; tk++) {
      int tok = tok0 + tk;
      if (tid < DD) xa[(size_t)tok * DD + tid] = accb[tk];
      else zout[(size_t)tok * DD + (tid - DD)] = accb[tk];
      if (two) zout[(size_t)tok * DD + (tid + 256 - DD)] = accc[tk];
    }
  }
}

// ---------------- head phase (per b): pool + 96x43 matmul ----------------
__device__ void phase_head(SMem& sm, int b, const float* __restrict__ t2,
                           const float* __restrict__ hw, const float* __restrict__ hb,
                           float* __restrict__ out) {
  int tid = threadIdx.x;
  if (tid < 2 * CC) {
    int part = tid / CC;
    int c = tid % CC;
    int l0 = part * 98;
    float acc = 0.f;
    for (int i = 0; i < 98; i++) acc += t2[((size_t)b * LL + l0 + i) * CC + c];
    sm.hd.part[part][c] = acc;
  }
  __syncthreads();
  if (tid < CC) sm.hd.pool[tid] = sm.hd.part[0][tid] + sm.hd.part[1][tid];
  __syncthreads();
  if (tid < NCLS) {
    float acc = hb[tid];
    for (int c = 0; c < CC; c++) acc += sm.hd.pool[c] * hw[c * NCLS + tid];
    out[b * NCLS + tid] = acc;
  }
}

// ---------------- the cooperative mega-kernel: whole network, per-b barriers ----------------
__global__ __launch_bounds__(256, 4) void k_mega(
    const float* __restrict__ x, const float* __restrict__ pw, const float* __restrict__ pb,
    const float* __restrict__ pos, const float* __restrict__ ln1w, const float* __restrict__ ln1b,
    const float* __restrict__ ipw, const float* __restrict__ cw, const float* __restrict__ cbp,
    const float* __restrict__ xpw, const float* __restrict__ dtw, const float* __restrict__ dtb,
    const float* __restrict__ alog, const float* __restrict__ dsp,
    const float* __restrict__ onw, const float* __restrict__ onb, const float* __restrict__ opw,
    const float* __restrict__ nw, const float* __restrict__ nbv,
    const float* __restrict__ hw, const float* __restrict__ hb,
    float* __restrict__ t, float* __restrict__ xa, float* __restrict__ z,
    float* __restrict__ xcT, float* __restrict__ dbl, float* __restrict__ ysum,
    float* __restrict__ t2, float* __restrict__ out,
    unsigned* __restrict__ bar, int gpb) {
  __shared__ SMem sm;
  int b = blockIdx.x / gpb;
  int rb = blockIdx.x % gpb;
  unsigned epoch = 0;

  // balanced contiguous partition of NV vblocks over gpb blocks (keeps workers spread)
#define PART_LOOP(NV) \
  for (int vb = (rb * (NV)) / gpb, vhi = ((rb + 1) * (NV)) / gpb; vb < vhi; vb++)

  // ---- patch embed ----
  PART_LOOP(LL / PTOK) {
    phase_patch(sm, b * LL + vb * PTOK, x, pw, pb, pos, t);
    __syncthreads();
  }
  bsync(bar, b, gpb, ++epoch);

  // ---- layer-0 LN + in_proj ----
  PART_LOOP(LL) {
    phase_lnproj(sm, b * LL + vb, t, ln1w, ln1b, ipw, xa, z);
    __syncthreads();
  }
  bsync(bar, b, gpb, ++epoch);

  // ---- 12 layers ----
  for (int i = 0; i < DEPTH; i++) {
    const float* cw_i = cw + (size_t)i * DD * 9;
    const float* cb_i = cbp + (size_t)i * DD;
    const float* xpw_i = xpw + (size_t)i * KDIR * DBLC * DD;
    const float* dtw_i = dtw + (size_t)i * KDIR * DD * RRANK;
    const float* dtb_i = dtb + (size_t)i * KDIR * DD;
    const float* alog_i = alog + (size_t)i * KDIR * DD * NSTATE;
    const float* ds_i = dsp + (size_t)i * KDIR * DD;
    const float* onw_i = onw + (size_t)i * DD;
    const float* onb_i = onb + (size_t)i * DD;
    const float* opw_i = opw + (size_t)i * DD * CC;

    PART_LOOP(KDIR * XT) {
      phase_xproj(sm, b, vb / XT, vb % XT, xa, cw_i, cb_i, xpw_i, xcT, dbl);
      __syncthreads();
    }
    bsync(bar, b, gpb, ++epoch);

    PART_LOOP(KDIR * (DD / 2)) {
      phase_scan(sm, b, vb % (DD / 2), vb / (DD / 2), xcT, dbl, dtw_i, dtb_i, alog_i, ds_i, ysum);
      __syncthreads();
    }
    bsync(bar, b, gpb, ++epoch);

    int mode = (i < DEPTH - 1) ? 1 : 2;
    const float* nlw = (mode == 1) ? ln1w + (size_t)(i + 1) * CC : nw;
    const float* nlb = (mode == 1) ? ln1b + (size_t)(i + 1) * CC : nbv;
    const float* ipw_n = ipw + (size_t)(i + 1) * CC * 2 * DD;  // one-past-end in mode 2, unused
    float* xout = (mode == 1) ? xa : t2;
    PART_LOOP(LL / GT) {
      phase_gateproj(sm, b, vb * GT, ysum, onw_i, onb_i, z, opw_i, t,
                     nlw, nlb, ipw_n, xout, z, mode);
      __syncthreads();
    }
    bsync(bar, b, gpb, ++epoch);
  }

  // ---- head (t2 of b complete after final bsync) ----
  if (rb == 0) phase_head(sm, b, t2, hw, hb, out);
#undef PART_LOOP
}

extern "C" void kernel_launch(void* const* d_in, const int* in_sizes, int n_in,
                              void* d_out, int out_size, void* d_ws, size_t ws_size,
                              hipStream_t stream) {
  const float* x       = (const float*)d_in[0];
  const float* patch_w = (const float*)d_in[1];
  const float* patch_b = (const float*)d_in[2];
  const float* pos     = (const float*)d_in[3];
  const float* ln1_w   = (const float*)d_in[4];
  const float* ln1_b   = (const float*)d_in[5];
  const float* ipw     = (const float*)d_in[6];
  const float* cw      = (const float*)d_in[7];
  const float* cb      = (const float*)d_in[8];
  const float* xpw     = (const float*)d_in[9];
  const float* dtw     = (const float*)d_in[10];
  const float* dtb     = (const float*)d_in[11];
  const float* alog    = (const float*)d_in[12];
  const float* dsp     = (const float*)d_in[13];
  const float* onw     = (const float*)d_in[14];
  const float* onb     = (const float*)d_in[15];
  const float* opw     = (const float*)d_in[16];
  const float* nw      = (const float*)d_in[17];
  const float* nrmb    = (const float*)d_in[18];
  const float* hw      = (const float*)d_in[19];
  const float* hb      = (const float*)d_in[20];
  float* out = (float*)d_out;

  float* wsf  = (float*)d_ws;
  float* t    = wsf;
  float* xa   = t    + BB * LL * CC;
  float* z    = xa   + BB * LL * DD;
  float* xcT  = z    + BB * LL * DD;
  float* dbl  = xcT  + BB * LL * DD;
  float* ysum = dbl  + BB * KDIR * DBKSZ;
  float* t2   = ysum + (size_t)KDIR * YSTRIDE;
  unsigned* bar = (unsigned*)(t2 + BB * LL * CC);

  // grid sizing: blocks-per-CU from the occupancy API (guards co-residency for the
  // cooperative launch), 256 CUs on MI355X, partitioned into 8 per-batch groups.
  static int gpb_cached = 0;
  if (!gpb_cached) {
    int nblk = 0;
    hipError_t e = hipOccupancyMaxActiveBlocksPerMultiprocessor(&nblk, k_mega, 256, 0);
    if (e != hipSuccess || nblk < 1) nblk = 1;
    if (nblk > 4) nblk = 4;             // LDS allows at most 4x40KB per CU; cap barrier cost
    gpb_cached = nblk * 256 / BB;       // blocks per batch group
  }
  int gpb = gpb_cached;

  hipMemsetAsync(bar, 0, BB * 32 * sizeof(unsigned), stream);

  void* kargs[] = {
      (void*)&x, (void*)&patch_w, (void*)&patch_b, (void*)&pos,
      (void*)&ln1_w, (void*)&ln1_b, (void*)&ipw, (void*)&cw, (void*)&cb,
      (void*)&xpw, (void*)&dtw, (void*)&dtb, (void*)&alog, (void*)&dsp,
      (void*)&onw, (void*)&onb, (void*)&opw, (void*)&nw, (void*)&nrmb,
      (void*)&hw, (void*)&hb,
      (void*)&t, (void*)&xa, (void*)&z, (void*)&xcT, (void*)&dbl, (void*)&ysum,
      (void*)&t2, (void*)&out, (void*)&bar, (void*)&gpb};
  hipLaunchCooperativeKernel((const void*)k_mega, dim3(BB * gpb), dim3(256),
                             kargs, 0, stream);
}

// Round 3
// 1068.215 us; speedup vs baseline: 3.4270x; 3.4270x over previous
//
#include <hip/hip_runtime.h>
#include <math.h>

#define BB 8
#define IMGS 224
#define PSZ 16
#define CC 96
#define DEPTH 12
#define NCLS 43
#define HH 14
#define WW 14
#define LL 196
#define DD 192
#define NSTATE 16
#define RRANK 6
#define KDIR 4
#define DBLC 38     // R + 2N = 6 + 32 (logical outputs of x_proj)
#define NSEG 16     // segments per chain
#define PTOK 4      // tokens per patch-embed block
// per-(b,k) dbl region: dtT[6][200] + B[196][16] + Ct[16][200]
#define TSTR 200    // row stride for dtT / Ct
#define OFF_B 1200
#define OFF_C 4336
#define DBKSZ 7552  // 1200 + 3136 + 3200 + 16 pad
#define XT 14       // tokens per x_proj tile (14 tiles -> 448 blocks)
#define XPAD 196    // x-tile row stride (mult of 4 => float4-aligned LDS reads)
#define GT 4        // tokens per gateproj block (392 blocks); 4 | 196 so same b, consecutive l
#define YSTRIDE (BB * DD * LL)  // per-direction ysum plane

__device__ __forceinline__ float wave_sum(float v) {
#pragma unroll
  for (int m = 32; m; m >>= 1) v += __shfl_xor(v, m, 64);
  return v;
}

__device__ __forceinline__ float silu_f(float x) {
  return x / (1.f + __expf(-x));
}

// ---------------- fused patch embed + LN(96) + layer-0 in_proj: 4 tokens/block ----------------
// patch matmul split 2-way over the 768-long reduction (192 threads), then per-wave LN
// (wave w = token w) and in_proj with each thread covering j=tid and j=tid+256.
__global__ void k_patchln(const float* __restrict__ x, const float* __restrict__ pw,
                          const float* __restrict__ pb, const float* __restrict__ pos,
                          const float* __restrict__ lw, const float* __restrict__ lb,
                          const float* __restrict__ ipw,
                          float* __restrict__ t, float* __restrict__ xa,
                          float* __restrict__ z) {
  __shared__ float s_px[PTOK][768];       // 12288 B
  __shared__ float s_part[2][PTOK][CC];   // 3072 B
  __shared__ float s_t[PTOK][CC];
  __shared__ float s_xn[PTOK][CC];
  int tok0 = blockIdx.x * PTOK;
  int tid = threadIdx.x;

  for (int tk = 0; tk < PTOK; tk++) {
    int tok = tok0 + tk;
    int b = tok / LL, l = tok % LL;
    int ph = l / WW, pwc = l % WW;
    for (int e = tid; e < 768; e += 256) {
      int ci = e >> 8, kh = (e >> 4) & 15, kw = e & 15;
      s_px[tk][e] = x[((size_t)(b * 3 + ci) * IMGS + ph * PSZ + kh) * IMGS + pwc * PSZ + kw];
    }
  }
  __syncthreads();

  if (tid < 2 * CC) {
    int c = tid % CC, eh = tid / CC;
    const float* wr = pw + (size_t)c * 768 + eh * 384;
    const float* p0 = &s_px[0][eh * 384];
    const float* p1 = &s_px[1][eh * 384];
    const float* p2 = &s_px[2][eh * 384];
    const float* p3 = &s_px[3][eh * 384];
    float a0 = 0.f, a1 = 0.f, a2 = 0.f, a3 = 0.f;
    for (int e = 0; e < 384; e++) {
      float wv = wr[e];
      a0 += p0[e] * wv;
      a1 += p1[e] * wv;
      a2 += p2[e] * wv;
      a3 += p3[e] * wv;
    }
    s_part[eh][0][c] = a0;
    s_part[eh][1][c] = a1;
    s_part[eh][2][c] = a2;
    s_part[eh][3][c] = a3;
  }
  __syncthreads();

  for (int idx = tid; idx < PTOK * CC; idx += 256) {
    int tk = idx / CC, c = idx % CC;
    int tok = tok0 + tk;
    float v = s_part[0][tk][c] + s_part[1][tk][c] + pb[c] + pos[(tok % LL) * CC + c];
    t[(size_t)tok * CC + c] = v;
    s_t[tk][c] = v;
  }
  __syncthreads();

  // per-wave LN(96); wave w = token w
  {
    int w = tid >> 6;
    int lane = tid & 63;
    float v0 = s_t[w][lane];
    float v1 = (lane < CC - 64) ? s_t[w][lane + 64] : 0.f;
    float mu = wave_sum(v0 + v1) * (1.f / CC);
    float d0 = v0 - mu;
    float d1 = (lane < CC - 64) ? (v1 - mu) : 0.f;
    float var = wave_sum(d0 * d0 + d1 * d1) * (1.f / CC);
    float rs = rsqrtf(var + 1e-6f);
    s_xn[w][lane] = d0 * rs * lw[lane] + lb[lane];
    if (lane < CC - 64) s_xn[w][lane + 64] = d1 * rs * lw[lane + 64] + lb[lane + 64];
  }
  __syncthreads();

  // in_proj: j = tid and (tid<128) j2 = tid+256; 384 outputs x 4 tokens
  {
    bool two = tid < (2 * DD - 256);
    float b0 = 0.f, b1 = 0.f, b2 = 0.f, b3 = 0.f;
    float c0 = 0.f, c1 = 0.f, c2 = 0.f, c3 = 0.f;
    for (int c = 0; c < CC; c++) {
      float x0 = s_xn[0][c], x1 = s_xn[1][c], x2 = s_xn[2][c], x3 = s_xn[3][c];
      float wv = ipw[(size_t)c * (2 * DD) + tid];
      b0 += x0 * wv; b1 += x1 * wv; b2 += x2 * wv; b3 += x3 * wv;
      if (two) {
        float wv2 = ipw[(size_t)c * (2 * DD) + tid + 256];
        c0 += x0 * wv2; c1 += x1 * wv2; c2 += x2 * wv2; c3 += x3 * wv2;
      }
    }
    float accb[PTOK] = {b0, b1, b2, b3};
    float accc[PTOK] = {c0, c1, c2, c3};
#pragma unroll
    for (int tk = 0; tk < PTOK; tk++) {
      int tok = tok0 + tk;
      if (tid < DD) xa[(size_t)tok * DD + tid] = accb[tk];
      else z[(size_t)tok * DD + (tid - DD)] = accb[tk];
      if (two) z[(size_t)tok * DD + (tid + 256 - DD)] = accc[tk];
    }
  }
}

// ---------------- x_proj v7: depthwise 3x3 conv FUSED in; k==0 blocks emit xcT ----------------
__global__ __launch_bounds__(256, 4) void k_xproj(
    const float* __restrict__ xa, const float* __restrict__ cw,
    const float* __restrict__ cb, const float* __restrict__ xpw,
    float* __restrict__ xcT, float* __restrict__ dbl) {
  __shared__ float s_w[DBLC * DD];    // 38 x 192 = 29184 B
  __shared__ float s_x[XT * XPAD];    // 14 x 196 = 10976 B
  int lt = blockIdx.x;  // 0..13
  int k = blockIdx.y;
  int b = blockIdx.z;
  int tid = threadIdx.x;
  int l0 = lt * XT;

  const float4* wsrc = (const float4*)(xpw + (size_t)k * DBLC * DD);
  float4* wdst = (float4*)s_w;
  for (int idx = tid; idx < (DBLC * DD) / 4; idx += 256) wdst[idx] = wsrc[idx];

  for (int idx = tid; idx < XT * (DD / 4); idx += 256) {
    int i = idx / (DD / 4);
    int d = (idx % (DD / 4)) * 4;
    int l = l0 + i;
    int lr = (k >= 2) ? (LL - 1 - l) : l;
    int src = (k & 1) ? ((lr % HH) * WW + lr / HH) : lr;
    int h = src / WW, w = src % WW;
    const float4 bv = *(const float4*)(cb + d);
    float a0 = bv.x, a1 = bv.y, a2 = bv.z, a3 = bv.w;
    if (h >= 1 && h < HH - 1 && w >= 1 && w < WW - 1) {
#pragma unroll
      for (int kh = 0; kh < 3; kh++) {
#pragma unroll
        for (int kw = 0; kw < 3; kw++) {
          const float4 v = *(const float4*)(
              xa + ((size_t)(b * LL + (h + kh - 1) * WW + (w + kw - 1))) * DD + d);
          int wo = kh * 3 + kw;
          a0 += v.x * cw[(d + 0) * 9 + wo];
          a1 += v.y * cw[(d + 1) * 9 + wo];
          a2 += v.z * cw[(d + 2) * 9 + wo];
          a3 += v.w * cw[(d + 3) * 9 + wo];
        }
      }
    } else {
      for (int kh = 0; kh < 3; kh++) {
        int hh = h + kh - 1;
        if (hh < 0 || hh >= HH) continue;
        for (int kw = 0; kw < 3; kw++) {
          int ww = w + kw - 1;
          if (ww < 0 || ww >= WW) continue;
          const float4 v = *(const float4*)(xa + ((size_t)(b * LL + hh * WW + ww)) * DD + d);
          int wo = kh * 3 + kw;
          a0 += v.x * cw[(d + 0) * 9 + wo];
          a1 += v.y * cw[(d + 1) * 9 + wo];
          a2 += v.z * cw[(d + 2) * 9 + wo];
          a3 += v.w * cw[(d + 3) * 9 + wo];
        }
      }
    }
    float4 r = make_float4(silu_f(a0), silu_f(a1), silu_f(a2), silu_f(a3));
    *(float4*)(s_x + i * XPAD + d) = r;
    if (k == 0) *(float4*)(xcT + ((size_t)(b * LL) + src) * DD + d) = r;  // src==l for k==0
  }
  __syncthreads();

  int li = tid & 15;
  int cbi = tid >> 4;       // 0..15 -> c = cbi, cbi+16, (cbi+32 if cbi<6)
  if (li >= XT) return;
  int l = l0 + li;
  float* base = dbl + (size_t)(b * KDIR + k) * DBKSZ;
  const float4* xr = (const float4*)(s_x + li * XPAD);
  const float4* w0 = (const float4*)(s_w + cbi * DD);
  const float4* w1 = (const float4*)(s_w + (cbi + 16) * DD);
  bool has2 = (cbi < DBLC - 32);
  const float4* w2 = has2 ? (const float4*)(s_w + (cbi + 32) * DD) : w0;
  float a0 = 0.f, a1 = 0.f, a2 = 0.f;
#pragma unroll 8
  for (int q = 0; q < DD / 4; q++) {
    float4 a = xr[q];
    float4 v0 = w0[q], v1 = w1[q], v2 = w2[q];
    a0 += a.x * v0.x + a.y * v0.y + a.z * v0.z + a.w * v0.w;
    a1 += a.x * v1.x + a.y * v1.y + a.z * v1.z + a.w * v1.w;
    a2 += a.x * v2.x + a.y * v2.y + a.z * v2.z + a.w * v2.w;
  }
  {
    int c = cbi;
    if (c < RRANK) base[c * TSTR + l] = a0;
    else base[OFF_B + l * NSTATE + (c - RRANK)] = a0;
  }
  {
    int c = cbi + 16;
    if (c < RRANK + NSTATE) base[OFF_B + l * NSTATE + (c - RRANK)] = a1;
    else base[OFF_C + (c - RRANK - NSTATE) * TSTR + l] = a1;
  }
  if (has2) {
    int c = cbi + 32;
    base[OFF_C + (c - RRANK - NSTATE) * TSTR + l] = a2;
  }
}

// ---------------- selective scan v13: s_h eliminated via in-pass shuffle reduction ----------------
// y[l] = sum_n C*h_local  (reduced across the 16 n-lanes during pass 1)
//      + sum_n C*exp(A*cumdt[l])*h_in[seg][n]  (post-combine correction loop)
// LDS 40KB -> ~16KB; occupancy 4 -> ~6-8 blocks/CU.
__global__ __launch_bounds__(256, 6) void k_scan(
    const float* __restrict__ xcT, const float* __restrict__ dbl,
    const float* __restrict__ dtw, const float* __restrict__ dtb,
    const float* __restrict__ alog, const float* __restrict__ dsv,
    float* __restrict__ ysum) {
  __shared__ float s_dt[2][LL];
  __shared__ float s_u[2][LL];
  __shared__ float s_xv[2][LL];
  __shared__ float s_cumdt[2][LL];
  __shared__ unsigned short s_src[LL];
  __shared__ float s_hin[2][NSEG][NSTATE];
  __shared__ float s_hend[2][NSEG][NSTATE];
  __shared__ float s_cum[2][NSEG][NSTATE];
  __shared__ float s_segsum[2][NSEG];
  __shared__ float s_yl[2][LL];   // local (within-segment) y, chain order
  __shared__ float s_yf[2][LL];   // final y, src (row-major spatial) order
  int tid = threadIdx.x;
  int s = tid >> 4;   // segment 0..15
  int n = tid & 15;   // state
  int bd = blockIdx.x;
  int dp = bd % (DD / 2);
  int d0 = dp * 2;
  int b = bd / (DD / 2);
  int k = blockIdx.y;  // direction 0..3

  // segment extents: first 4 have 13 steps, rest 12 (4*13 + 12*12 = 196)
  int len = (s < 4) ? 13 : 12;
  int l0 = s * 12 + ((s < 4) ? s : 4);

  float A0 = -__expf(alog[((size_t)k * DD + d0) * NSTATE + n]);
  float A1 = -__expf(alog[((size_t)k * DD + d0 + 1) * NSTATE + n]);
  float Dsc0 = dsv[k * DD + d0];
  float Dsc1 = dsv[k * DD + d0 + 1];
  const float* blp = dbl + (size_t)(b * KDIR + k) * DBKSZ;

  // ---- phase 0: parallel per-token precompute; dt-rows + xv loaded ONCE for the pair ----
  if (tid < LL) {
    int l = tid;
    float r[RRANK];
#pragma unroll
    for (int rr = 0; rr < RRANK; rr++) r[rr] = blp[rr * TSTR + l];
    const float* wp0 = dtw + ((size_t)k * DD + d0) * RRANK;
    const float* wp1 = wp0 + RRANK;
    float m0 = dtb[k * DD + d0], m1 = dtb[k * DD + d0 + 1];
#pragma unroll
    for (int rr = 0; rr < RRANK; rr++) { m0 += r[rr] * wp0[rr]; m1 += r[rr] * wp1[rr]; }
    float dt0 = (m0 > 20.f) ? m0 : __logf(1.f + __expf(m0));
    float dt1 = (m1 > 20.f) ? m1 : __logf(1.f + __expf(m1));
    int lr = (k >= 2) ? (LL - 1 - l) : l;
    int src = (k & 1) ? ((lr % HH) * WW + lr / HH) : lr;
    float2 xv = *(const float2*)(xcT + ((size_t)b * LL + src) * DD + d0);
    s_dt[0][l] = dt0; s_dt[1][l] = dt1;
    s_u[0][l] = dt0 * xv.x; s_u[1][l] = dt1 * xv.y;
    s_xv[0][l] = xv.x; s_xv[1][l] = xv.y;
    s_src[l] = (unsigned short)src;
  }
  __syncthreads();

  // per-token inclusive prefix sum of dt within its segment (both d's)
  if (tid < LL) {
    int l = tid;
    int myseg = (l < 52) ? (l / 13) : (4 + (l - 52) / 12);
    int sl0 = myseg * 12 + ((myseg < 4) ? myseg : 4);
    float a0 = 0.f, a1 = 0.f;
    for (int j = sl0; j <= l; j++) { a0 += s_dt[0][j]; a1 += s_dt[1][j]; }
    s_cumdt[0][l] = a0; s_cumdt[1][l] = a1;
    int slen = (myseg < 4) ? 13 : 12;
    if (l == sl0 + slen - 1) { s_segsum[0][myseg] = a0; s_segsum[1][myseg] = a1; }
  }
  __syncthreads();

  // ---- pass 1: serial chains + in-pass C-weighted n-reduction (4 shfl per term) ----
  const float* crow = blp + OFF_C + n * TSTR;
  float Breg[13];
#pragma unroll
  for (int i = 0; i < 13; i++) {
    int li = (i < len) ? (l0 + i) : l0;
    Breg[i] = blp[OFF_B + li * NSTATE + n];
  }
  float h0 = 0.f, h1 = 0.f;
#pragma unroll
  for (int i = 0; i < 13; i++) {
    if (i < len) {  // wave-uniform: segments 0..3 are exactly wave 0
      int l = l0 + i;
      float a0 = __expf(s_dt[0][l] * A0);
      float a1 = __expf(s_dt[1][l] * A1);
      h0 = h0 * a0 + s_u[0][l] * Breg[i];
      h1 = h1 * a1 + s_u[1][l] * Breg[i];
      float Cv = crow[l];
      float t0 = h0 * Cv, t1 = h1 * Cv;
#pragma unroll
      for (int m = 1; m < 16; m <<= 1) {
        t0 += __shfl_xor(t0, m, 64);
        t1 += __shfl_xor(t1, m, 64);
      }
      if (n == 0) { s_yl[0][l] = t0; s_yl[1][l] = t1; }
    }
  }
  s_hend[0][s][n] = h0; s_hend[1][s][n] = h1;
  s_cum[0][s][n] = __expf(A0 * s_segsum[0][s]);
  s_cum[1][s][n] = __expf(A1 * s_segsum[1][s]);
  __syncthreads();

  // ---- combine: each (s,n) thread computes h_in for both d's ----
  {
    float hh0 = 0.f, hh1 = 0.f;
    for (int ss = 0; ss < s; ss++) {
      hh0 = s_cum[0][ss][n] * hh0 + s_hend[0][ss][n];
      hh1 = s_cum[1][ss][n] * hh1 + s_hend[1][ss][n];
    }
    s_hin[0][s][n] = hh0; s_hin[1][s][n] = hh1;
  }
  __syncthreads();

  // ---- correction: add C*exp(A*cumdt)*h_in, reduce over n, scatter to src order ----
  {
    float hin0 = s_hin[0][s][n], hin1 = s_hin[1][s][n];
#pragma unroll
    for (int i = 0; i < 13; i++) {
      if (i < len) {
        int l = l0 + i;
        float Cv = crow[l];
        float t0 = __expf(A0 * s_cumdt[0][l]) * hin0 * Cv;
        float t1 = __expf(A1 * s_cumdt[1][l]) * hin1 * Cv;
#pragma unroll
        for (int m = 1; m < 16; m <<= 1) {
          t0 += __shfl_xor(t0, m, 64);
          t1 += __shfl_xor(t1, m, 64);
        }
        if (n == 0) {
          int sr = s_src[l];
          s_yf[0][sr] = s_yl[0][l] + t0 + Dsc0 * s_xv[0][l];
          s_yf[1][sr] = s_yl[1][l] + t1 + Dsc1 * s_xv[1][l];
        }
      }
    }
  }
  __syncthreads();
  if (tid < LL) {
    size_t base = (size_t)k * YSTRIDE + ((size_t)b * DD + d0) * LL;
    ysum[base + tid] = s_yf[0][tid];
    ysum[base + LL + tid] = s_yf[1][tid];
  }
}

// ---- fused gate+proj v5: per-wave LN(192) ----
// mode 1: out_proj + residual + next-layer LN(96)+in_proj -> xa,zout
// mode 2: out_proj + residual + FINAL LN * (1/L) -> t2 (passed via xa)
__global__ void k_gateproj(const float* __restrict__ ys,
                           const float* __restrict__ onw, const float* __restrict__ onb,
                           const float* __restrict__ z, const float* __restrict__ opw,
                           float* __restrict__ t,
                           const float* __restrict__ nlw, const float* __restrict__ nlb,
                           const float* __restrict__ ipw,
                           float* __restrict__ xa, float* __restrict__ zout, int mode) {
  __shared__ float s_g[GT][DD];
  __shared__ float s_t[GT][CC];
  __shared__ float s_x[GT][CC];
  __shared__ float s_p[4][GT][CC];
  int tok0 = blockIdx.x * GT;
  int b = tok0 / LL;   // GT | LL so all 4 tokens share b
  int l0 = tok0 % LL;  // consecutive l0..l0+3
  int tid = threadIdx.x;

  // stage 1a: per-d float4 row loads (4 tokens at once), sum 4 direction planes, transpose
  if (tid < DD) {
    size_t base = ((size_t)b * DD + tid) * LL + l0;
    float4 v0 = *(const float4*)(ys + base);
    float4 v1 = *(const float4*)(ys + (size_t)YSTRIDE + base);
    float4 v2 = *(const float4*)(ys + 2 * (size_t)YSTRIDE + base);
    float4 v3 = *(const float4*)(ys + 3 * (size_t)YSTRIDE + base);
    s_g[0][tid] = v0.x + v1.x + v2.x + v3.x;
    s_g[1][tid] = v0.y + v1.y + v2.y + v3.y;
    s_g[2][tid] = v0.z + v1.z + v2.z + v3.z;
    s_g[3][tid] = v0.w + v1.w + v2.w + v3.w;
  }
  __syncthreads();

  // stage 1b: per-wave LN(192)+silu-gate; wave w = token w; no cross-wave comms
  {
    int w = tid >> 6;
    int lane = tid & 63;
    if (w < GT) {
      int tok = tok0 + w;
      float v0 = s_g[w][lane];
      float v1 = s_g[w][lane + 64];
      float v2 = s_g[w][lane + 128];
      float mu = wave_sum(v0 + v1 + v2) * (1.f / DD);
      float d0 = v0 - mu, d1 = v1 - mu, d2 = v2 - mu;
      float var = wave_sum(d0 * d0 + d1 * d1 + d2 * d2) * (1.f / DD);
      float rs = rsqrtf(var + 1e-6f);
      const float* zp = z + (size_t)tok * DD;
      s_g[w][lane]       = (d0 * rs * onw[lane] + onb[lane]) * silu_f(zp[lane]);
      s_g[w][lane + 64]  = (d1 * rs * onw[lane + 64] + onb[lane + 64]) * silu_f(zp[lane + 64]);
      s_g[w][lane + 128] = (d2 * rs * onw[lane + 128] + onb[lane + 128]) * silu_f(zp[lane + 128]);
    }
  }
  __syncthreads();

  // stage 2: out_proj partials, weights read once for 4 tokens
  {
    int c = tid % CC;
    int part = tid / CC;  // 0..3
    int dlo = part * 48;
    float a0 = 0.f, a1 = 0.f, a2 = 0.f, a3 = 0.f;
#pragma unroll 8
    for (int j = 0; j < 48; j++) {
      float wv = opw[(size_t)(dlo + j) * CC + c];
      a0 += s_g[0][dlo + j] * wv;
      a1 += s_g[1][dlo + j] * wv;
      a2 += s_g[2][dlo + j] * wv;
      a3 += s_g[3][dlo + j] * wv;
    }
    s_p[part][0][c] = a0;
    s_p[part][1][c] = a1;
    s_p[part][2][c] = a2;
    s_p[part][3][c] = a3;
  }
  __syncthreads();
  // residual + t update
  {
    int tk = tid / CC;  // 0..3
    int c = tid % CC;
    float tn = t[(size_t)(tok0 + tk) * CC + c] +
               s_p[0][tk][c] + s_p[1][tk][c] + s_p[2][tk][c] + s_p[3][tk][c];
    t[(size_t)(tok0 + tk) * CC + c] = tn;
    s_t[tk][c] = tn;
  }
  __syncthreads();

  // stage 3: LN(96) with nlw/nlb (next layer's ln1, or final norm in mode 2); per-wave
  {
    int w = tid >> 6;
    int lane = tid & 63;
    if (w < GT) {
      float v0 = s_t[w][lane];
      float v1 = (lane < CC - 64) ? s_t[w][lane + 64] : 0.f;
      float mu2 = wave_sum(v0 + v1) * (1.f / CC);
      float d0 = v0 - mu2;
      float d1 = (lane < CC - 64) ? (v1 - mu2) : 0.f;
      float var2 = wave_sum(d0 * d0 + d1 * d1) * (1.f / CC);
      float rs2 = rsqrtf(var2 + 1e-6f);
      s_x[w][lane] = d0 * rs2 * nlw[lane] + nlb[lane];
      if (lane < CC - 64) s_x[w][lane + 64] = d1 * rs2 * nlw[lane + 64] + nlb[lane + 64];
    }
  }
  __syncthreads();

  if (mode == 2) {
    int tk = tid / CC;
    int c = tid % CC;
    xa[(size_t)(tok0 + tk) * CC + c] = s_x[tk][c] * (1.f / LL);
    return;
  }

  // stage 4: next layer's in_proj, weights read once for 4 tokens
  {
    float b0 = 0.f, b1 = 0.f, b2 = 0.f, b3 = 0.f;
    for (int c = 0; c < CC; c++) {
      float wv = ipw[(size_t)c * (2 * DD) + tid];
      b0 += s_x[0][c] * wv;
      b1 += s_x[1][c] * wv;
      b2 += s_x[2][c] * wv;
      b3 += s_x[3][c] * wv;
    }
    float acc[GT] = {b0, b1, b2, b3};
#pragma unroll
    for (int tk = 0; tk < GT; tk++) {
      int tok = tok0 + tk;
      if (tid < DD) xa[(size_t)tok * DD + tid] = acc[tk];
      else zout[(size_t)tok * DD + (tid - DD)] = acc[tk];
    }
  }
}

// ---------------- pooled head: 8 blocks x 256 thr; 2-way parallel pool + 96x43 matmul ----------------
__global__ void k_head(const float* __restrict__ t2, const float* __restrict__ hw,
                       const float* __restrict__ hb, float* __restrict__ out) {
  __shared__ float s_part[2][CC];
  __shared__ float s_pool[CC];
  int b = blockIdx.x;
  int tid = threadIdx.x;
  if (tid < 2 * CC) {
    int part = tid / CC;
    int c = tid % CC;
    int l0 = part * 98;
    float acc = 0.f;
    for (int i = 0; i < 98; i++) acc += t2[((size_t)b * LL + l0 + i) * CC + c];
    s_part[part][c] = acc;
  }
  __syncthreads();
  if (tid < CC) s_pool[tid] = s_part[0][tid] + s_part[1][tid];
  __syncthreads();
  if (tid < NCLS) {
    float acc = hb[tid];
    for (int c = 0; c < CC; c++) acc += s_pool[c] * hw[c * NCLS + tid];
    out[b * NCLS + tid] = acc;
  }
}

extern "C" void kernel_launch(void* const* d_in, const int* in_sizes, int n_in,
                              void* d_out, int out_size, void* d_ws, size_t ws_size,
                              hipStream_t stream) {
  const float* x       = (const float*)d_in[0];
  const float* patch_w = (const float*)d_in[1];
  const float* patch_b = (const float*)d_in[2];
  const float* pos     = (const float*)d_in[3];
  const float* ln1_w   = (const float*)d_in[4];
  const float* ln1_b   = (const float*)d_in[5];
  const float* ipw     = (const float*)d_in[6];
  const float* cw      = (const float*)d_in[7];
  const float* cb      = (const float*)d_in[8];
  const float* xpw     = (const float*)d_in[9];
  const float* dtw     = (const float*)d_in[10];
  const float* dtb     = (const float*)d_in[11];
  const float* alog    = (const float*)d_in[12];
  const float* dsp     = (const float*)d_in[13];
  const float* onw     = (const float*)d_in[14];
  const float* onb     = (const float*)d_in[15];
  const float* opw     = (const float*)d_in[16];
  const float* nw      = (const float*)d_in[17];
  const float* nb      = (const float*)d_in[18];
  const float* hw      = (const float*)d_in[19];
  const float* hb      = (const float*)d_in[20];
  float* out = (float*)d_out;

  // Workspace (all separate; ws_size = 256 MiB):
  float* wsf  = (float*)d_ws;
  float* t    = wsf;
  float* xa   = t    + BB * LL * CC;
  float* z    = xa   + BB * LL * DD;
  float* xcT  = z    + BB * LL * DD;
  float* dbl  = xcT  + BB * LL * DD;
  float* ysum = dbl  + BB * KDIR * DBKSZ;
  float* t2   = ysum + (size_t)KDIR * YSTRIDE;

  // fused patch embed + layer-0 LN + in_proj
  k_patchln<<<BB * LL / PTOK, 256, 0, stream>>>(x, patch_w, patch_b, pos,
                                                ln1_w, ln1_b, ipw, t, xa, z);

  for (int i = 0; i < DEPTH; i++) {
    // conv fused into x_proj; k==0 blocks emit xcT for the scan
    k_xproj<<<dim3(LL / XT, KDIR, BB), 256, 0, stream>>>(
        xa, cw + i * DD * 9, cb + i * DD,
        xpw + (size_t)i * KDIR * DBLC * DD, xcT, dbl);
    // one block per (b, d-pair, k): 768 x 4 blocks
    k_scan<<<dim3(BB * DD / 2, KDIR), 256, 0, stream>>>(
        xcT, dbl, dtw + (size_t)i * KDIR * DD * RRANK, dtb + i * KDIR * DD,
        alog + (size_t)i * KDIR * DD * NSTATE, dsp + i * KDIR * DD, ysum);
    if (i < DEPTH - 1) {
      k_gateproj<<<BB * LL / GT, 384, 0, stream>>>(
          ysum, onw + i * DD, onb + i * DD, z, opw + (size_t)i * DD * CC, t,
          ln1_w + (i + 1) * CC, ln1_b + (i + 1) * CC, ipw + (size_t)(i + 1) * CC * 2 * DD,
          xa, z, 1);
    } else {
      k_gateproj<<<BB * LL / GT, 384, 0, stream>>>(
          ysum, onw + i * DD, onb + i * DD, z, opw + (size_t)i * DD * CC, t,
          nw, nb, ipw, t2, z, 2);
    }
  }

  k_head<<<BB, 256, 0, stream>>>(t2, hw, hb, out);
}

// Round 4
// 779.454 us; speedup vs baseline: 4.6965x; 1.3705x over previous
//
#include <hip/hip_runtime.h>
#include <math.h>

#define BB 8
#define IMGS 224
#define PSZ 16
#define CC 96
#define DEPTH 12
#define NCLS 43
#define HH 14
#define WW 14
#define LL 196
#define DD 192
#define NSTATE 16
#define RRANK 6
#define KDIR 4
#define DBLC 38     // R + 2N = 6 + 32 (logical outputs of x_proj)
#define NSEG 16     // segments per chain
#define PTOK 4      // tokens per patch-embed block
// per-(b,k) dbl region: dtT[6][200] + B[196][16] + Ct[16][200]
#define TSTR 200    // row stride for dtT / Ct
#define OFF_B 1200
#define OFF_C 4336
#define DBKSZ 7552  // 1200 + 3136 + 3200 + 16 pad
#define XT 28       // tokens per x_proj tile (7 tiles -> 224 blocks, <=1/CU)
#define XPAD 196    // x-tile row stride (mult of 4 => float4-aligned LDS reads)
#define GT 7        // tokens per gateproj block (224 blocks, <=1/CU); 7 | 196 so same b
#define YSTRIDE (BB * DD * LL)  // per-direction ysum plane

__device__ __forceinline__ float wave_sum(float v) {
#pragma unroll
  for (int m = 32; m; m >>= 1) v += __shfl_xor(v, m, 64);
  return v;
}

__device__ __forceinline__ float silu_f(float x) {
  return x / (1.f + __expf(-x));
}

// ---------------- patch embed: 4 tokens/block, LDS-staged patch, contiguous weight reads ----------------
__global__ void k_patch(const float* __restrict__ x, const float* __restrict__ pw,
                        const float* __restrict__ pb, const float* __restrict__ pos,
                        float* __restrict__ t) {
  __shared__ float s_x[PTOK][768];  // 3*16*16 per token
  int tok0 = blockIdx.x * PTOK;
  for (int tk = 0; tk < PTOK; tk++) {
    int tok = tok0 + tk;
    int b = tok / LL, l = tok % LL;
    int ph = l / WW, pwc = l % WW;
    for (int e = threadIdx.x; e < 768; e += 128) {
      int ci = e >> 8, kh = (e >> 4) & 15, kw = e & 15;
      s_x[tk][e] = x[((size_t)(b * 3 + ci) * IMGS + ph * PSZ + kh) * IMGS + pwc * PSZ + kw];
    }
  }
  __syncthreads();
  if (threadIdx.x < CC) {
    int c = threadIdx.x;
    float a0 = pb[c], a1 = a0, a2 = a0, a3 = a0;
    const float* wr = pw + (size_t)c * 768;
    for (int e = 0; e < 768; e++) {
      float wv = wr[e];
      a0 += s_x[0][e] * wv;
      a1 += s_x[1][e] * wv;
      a2 += s_x[2][e] * wv;
      a3 += s_x[3][e] * wv;
    }
    float acc[4] = {a0, a1, a2, a3};
    for (int tk = 0; tk < PTOK; tk++) {
      int tok = tok0 + tk;
      t[(size_t)tok * CC + c] = acc[tk] + pos[(tok % LL) * CC + c];
    }
  }
}

// ---------------- fused LN(96) + in_proj -> xa,z (B,L,D each); layer 0 only ----------------
__global__ void k_lnproj(const float* __restrict__ t, const float* __restrict__ w,
                         const float* __restrict__ bias, const float* __restrict__ ipw,
                         float* __restrict__ xa, float* __restrict__ z) {
  __shared__ float s_x[CC];
  int tok = blockIdx.x;
  int tid = threadIdx.x;
  if (tid < 64) {
    int lane = tid;
    const float* p = t + (size_t)tok * CC;
    float v0 = p[lane];
    float v1 = (lane < CC - 64) ? p[lane + 64] : 0.f;
    float mu = wave_sum(v0 + v1) * (1.f / CC);
    float d0 = v0 - mu;
    float d1 = (lane < CC - 64) ? (v1 - mu) : 0.f;
    float var = wave_sum(d0 * d0 + d1 * d1) * (1.f / CC);
    float rs = rsqrtf(var + 1e-6f);
    s_x[lane] = d0 * rs * w[lane] + bias[lane];
    if (lane < CC - 64) s_x[lane + 64] = d1 * rs * w[lane + 64] + bias[lane + 64];
  }
  __syncthreads();
  int j = tid;  // 0..383
  float acc = 0.f;
  for (int c = 0; c < CC; c++) acc += s_x[c] * ipw[(size_t)c * (2 * DD) + j];
  if (j < DD) xa[(size_t)tok * DD + j] = acc;
  else z[(size_t)tok * DD + (j - DD)] = acc;
}

// ---------------- x_proj v8: conv fused; XT=28 -> 224 blocks (<=1/CU), weight-stage amortized ----------------
__global__ __launch_bounds__(256) void k_xproj(
    const float* __restrict__ xa, const float* __restrict__ cw,
    const float* __restrict__ cb, const float* __restrict__ xpw,
    float* __restrict__ xcT, float* __restrict__ dbl) {
  __shared__ float s_w[DBLC * DD];    // 38 x 192 = 29184 B
  __shared__ float s_x[XT * XPAD];    // 28 x 196 = 21952 B
  int lt = blockIdx.x;  // 0..6
  int k = blockIdx.y;
  int b = blockIdx.z;
  int tid = threadIdx.x;
  int l0 = lt * XT;

  const float4* wsrc = (const float4*)(xpw + (size_t)k * DBLC * DD);
  float4* wdst = (float4*)s_w;
  for (int idx = tid; idx < (DBLC * DD) / 4; idx += 256) wdst[idx] = wsrc[idx];

  // fused depthwise conv 3x3 + bias + SiLU for the tile's 28 src tokens
  for (int idx = tid; idx < XT * (DD / 4); idx += 256) {
    int i = idx / (DD / 4);
    int d = (idx % (DD / 4)) * 4;
    int l = l0 + i;
    int lr = (k >= 2) ? (LL - 1 - l) : l;
    int src = (k & 1) ? ((lr % HH) * WW + lr / HH) : lr;
    int h = src / WW, w = src % WW;
    const float4 bv = *(const float4*)(cb + d);
    float a0 = bv.x, a1 = bv.y, a2 = bv.z, a3 = bv.w;
    if (h >= 1 && h < HH - 1 && w >= 1 && w < WW - 1) {
#pragma unroll
      for (int kh = 0; kh < 3; kh++) {
#pragma unroll
        for (int kw = 0; kw < 3; kw++) {
          const float4 v = *(const float4*)(
              xa + ((size_t)(b * LL + (h + kh - 1) * WW + (w + kw - 1))) * DD + d);
          int wo = kh * 3 + kw;
          a0 += v.x * cw[(d + 0) * 9 + wo];
          a1 += v.y * cw[(d + 1) * 9 + wo];
          a2 += v.z * cw[(d + 2) * 9 + wo];
          a3 += v.w * cw[(d + 3) * 9 + wo];
        }
      }
    } else {
      for (int kh = 0; kh < 3; kh++) {
        int hh = h + kh - 1;
        if (hh < 0 || hh >= HH) continue;
        for (int kw = 0; kw < 3; kw++) {
          int ww = w + kw - 1;
          if (ww < 0 || ww >= WW) continue;
          const float4 v = *(const float4*)(xa + ((size_t)(b * LL + hh * WW + ww)) * DD + d);
          int wo = kh * 3 + kw;
          a0 += v.x * cw[(d + 0) * 9 + wo];
          a1 += v.y * cw[(d + 1) * 9 + wo];
          a2 += v.z * cw[(d + 2) * 9 + wo];
          a3 += v.w * cw[(d + 3) * 9 + wo];
        }
      }
    }
    float4 r = make_float4(silu_f(a0), silu_f(a1), silu_f(a2), silu_f(a3));
    *(float4*)(s_x + i * XPAD + d) = r;
    if (k == 0) *(float4*)(xcT + ((size_t)(b * LL) + src) * DD + d) = r;  // src==l for k==0
  }
  __syncthreads();

  // matmul: 32 li-slots x 8 c-blocks; each thread: c = cbi + 8j, j=0..4 (c<38)
  int li = tid & 31;
  int cbi = tid >> 5;   // 0..7
  if (li >= XT) return; // 224 of 256 active
  int l = l0 + li;
  float* base = dbl + (size_t)(b * KDIR + k) * DBKSZ;
  const float4* xr = (const float4*)(s_x + li * XPAD);
  const float4* wp[5];
#pragma unroll
  for (int j = 0; j < 5; j++) {
    int c = cbi + 8 * j;
    wp[j] = (const float4*)(s_w + ((c < DBLC) ? c : 0) * DD);
  }
  float a[5] = {0.f, 0.f, 0.f, 0.f, 0.f};
#pragma unroll 4
  for (int q = 0; q < DD / 4; q++) {
    float4 av = xr[q];
#pragma unroll
    for (int j = 0; j < 5; j++) {
      float4 wv = wp[j][q];
      a[j] += av.x * wv.x + av.y * wv.y + av.z * wv.z + av.w * wv.w;
    }
  }
#pragma unroll
  for (int j = 0; j < 5; j++) {
    int c = cbi + 8 * j;
    if (c >= DBLC) continue;
    if (c < RRANK) base[c * TSTR + l] = a[j];
    else if (c < RRANK + NSTATE) base[OFF_B + l * NSTATE + (c - RRANK)] = a[j];
    else base[OFF_C + (c - RRANK - NSTATE) * TSTR + l] = a[j];
  }
}

// ---------------- selective scan v12 (proven): one block per (b, d-PAIR, k) ----------------
__global__ __launch_bounds__(256, 4) void k_scan(
    const float* __restrict__ xcT, const float* __restrict__ dbl,
    const float* __restrict__ dtw, const float* __restrict__ dtb,
    const float* __restrict__ alog, const float* __restrict__ dsv,
    float* __restrict__ ysum) {
  __shared__ float s_h[2][NSTATE][LL + 1];  // 25.2 KB; stride 197 conflict-free
  __shared__ float s_dt[2][LL];
  __shared__ float s_u[2][LL];
  __shared__ float s_xv[2][LL];
  __shared__ float s_cumdt[2][LL];
  __shared__ unsigned short s_src[LL];
  __shared__ float s_hin[2][NSEG][NSTATE];
  __shared__ float s_hend[2][NSEG][NSTATE];
  __shared__ float s_cum[2][NSEG][NSTATE];
  __shared__ float s_segsum[2][NSEG];
  __shared__ float s_A[2][NSTATE];
  __shared__ float s_y[2][LL];
  int tid = threadIdx.x;
  int s = tid >> 4;   // segment 0..15
  int n = tid & 15;   // state
  int bd = blockIdx.x;
  int dp = bd % (DD / 2);
  int d0 = dp * 2;
  int b = bd / (DD / 2);
  int k = blockIdx.y;  // direction 0..3

  // segment extents: first 4 have 13 steps, rest 12 (4*13 + 12*12 = 196)
  int len = (s < 4) ? 13 : 12;
  int l0 = s * 12 + ((s < 4) ? s : 4);

  float A0 = -__expf(alog[((size_t)k * DD + d0) * NSTATE + n]);
  float A1 = -__expf(alog[((size_t)k * DD + d0 + 1) * NSTATE + n]);
  float Dsc0 = dsv[k * DD + d0];
  float Dsc1 = dsv[k * DD + d0 + 1];
  const float* blp = dbl + (size_t)(b * KDIR + k) * DBKSZ;
  if (tid < NSTATE) { s_A[0][tid] = A0; s_A[1][tid] = A1; }

  // ---- phase 0: parallel per-token precompute; dt-rows + xv loaded ONCE for the pair ----
  if (tid < LL) {
    int l = tid;
    float r[RRANK];
#pragma unroll
    for (int rr = 0; rr < RRANK; rr++) r[rr] = blp[rr * TSTR + l];
    const float* wp0 = dtw + ((size_t)k * DD + d0) * RRANK;
    const float* wp1 = wp0 + RRANK;
    float m0 = dtb[k * DD + d0], m1 = dtb[k * DD + d0 + 1];
#pragma unroll
    for (int rr = 0; rr < RRANK; rr++) { m0 += r[rr] * wp0[rr]; m1 += r[rr] * wp1[rr]; }
    float dt0 = (m0 > 20.f) ? m0 : __logf(1.f + __expf(m0));
    float dt1 = (m1 > 20.f) ? m1 : __logf(1.f + __expf(m1));
    int lr = (k >= 2) ? (LL - 1 - l) : l;
    int src = (k & 1) ? ((lr % HH) * WW + lr / HH) : lr;
    float2 xv = *(const float2*)(xcT + ((size_t)b * LL + src) * DD + d0);
    s_dt[0][l] = dt0; s_dt[1][l] = dt1;
    s_u[0][l] = dt0 * xv.x; s_u[1][l] = dt1 * xv.y;
    s_xv[0][l] = xv.x; s_xv[1][l] = xv.y;
    s_src[l] = (unsigned short)src;
  }
  __syncthreads();

  // per-token inclusive prefix sum of dt within its segment (both d's)
  if (tid < LL) {
    int l = tid;
    int myseg = (l < 52) ? (l / 13) : (4 + (l - 52) / 12);
    int sl0 = myseg * 12 + ((myseg < 4) ? myseg : 4);
    float a0 = 0.f, a1 = 0.f;
    for (int j = sl0; j <= l; j++) { a0 += s_dt[0][j]; a1 += s_dt[1][j]; }
    s_cumdt[0][l] = a0; s_cumdt[1][l] = a1;
    int slen = (myseg < 4) ? 13 : 12;
    if (l == sl0 + slen - 1) { s_segsum[0][myseg] = a0; s_segsum[1][myseg] = a1; }
  }
  __syncthreads();

  // ---- pass 1: two independent serial chains; B prefetched ONCE for the pair ----
  float Breg[13];
#pragma unroll
  for (int i = 0; i < 13; i++) {
    int li = (i < len) ? (l0 + i) : l0;
    Breg[i] = blp[OFF_B + li * NSTATE + n];
  }
  float h0 = 0.f, h1 = 0.f;
#pragma unroll
  for (int i = 0; i < 13; i++) {
    if (i < len) {
      int l = l0 + i;
      float a0 = __expf(s_dt[0][l] * A0);
      float a1 = __expf(s_dt[1][l] * A1);
      h0 = h0 * a0 + s_u[0][l] * Breg[i];
      h1 = h1 * a1 + s_u[1][l] * Breg[i];
      s_h[0][n][l] = h0;
      s_h[1][n][l] = h1;
    }
  }
  s_hend[0][s][n] = h0; s_hend[1][s][n] = h1;
  s_cum[0][s][n] = __expf(A0 * s_segsum[0][s]);
  s_cum[1][s][n] = __expf(A1 * s_segsum[1][s]);
  __syncthreads();

  // ---- combine: each (s,n) thread computes h_in for both d's (independent FMA chains) ----
  {
    float hh0 = 0.f, hh1 = 0.f;
    for (int ss = 0; ss < s; ss++) {
      hh0 = s_cum[0][ss][n] * hh0 + s_hend[0][ss][n];
      hh1 = s_cum[1][ss][n] * hh1 + s_hend[1][ss][n];
    }
    s_hin[0][s][n] = hh0; s_hin[1][s][n] = hh1;
  }
  __syncthreads();

  // ---- phase 2: y per token; C loaded ONCE for the pair ----
  if (tid < LL) {
    int l = tid;
    int myseg = (l < 52) ? (l / 13) : (4 + (l - 52) / 12);
    float cd0 = s_cumdt[0][l], cd1 = s_cumdt[1][l];
    const float* q = blp + OFF_C + l;  // Ct[nn][l], stride TSTR
    float y0 = 0.f, y1 = 0.f;
#pragma unroll
    for (int nn = 0; nn < NSTATE; nn++) {
      float Cv = q[nn * TSTR];
      float hf0 = s_h[0][nn][l] + __expf(s_A[0][nn] * cd0) * s_hin[0][myseg][nn];
      float hf1 = s_h[1][nn][l] + __expf(s_A[1][nn] * cd1) * s_hin[1][myseg][nn];
      y0 += hf0 * Cv;
      y1 += hf1 * Cv;
    }
    y0 += Dsc0 * s_xv[0][l];
    y1 += Dsc1 * s_xv[1][l];
    int src = s_src[l];
    s_y[0][src] = y0;
    s_y[1][src] = y1;
  }
  __syncthreads();
  if (tid < LL) {
    size_t base = (size_t)k * YSTRIDE + ((size_t)b * DD + d0) * LL;
    ysum[base + tid] = s_y[0][tid];
    ysum[base + LL + tid] = s_y[1][tid];
  }
}

// ---- fused gate+proj v6: GT=7 tokens/block, 448 threads (7 waves), 224 blocks (<=1/CU) ----
// wave w (0..6) owns token w for both LN passes; out_proj/in_proj weights read once for 7 tokens.
// mode 1: out_proj + residual + next-layer LN(96)+in_proj -> xa,zout
// mode 2: out_proj + residual + FINAL LN * (1/L) -> t2 (passed via xa)
__global__ void k_gateproj(const float* __restrict__ ys,
                           const float* __restrict__ onw, const float* __restrict__ onb,
                           const float* __restrict__ z, const float* __restrict__ opw,
                           float* __restrict__ t,
                           const float* __restrict__ nlw, const float* __restrict__ nlb,
                           const float* __restrict__ ipw,
                           float* __restrict__ xa, float* __restrict__ zout, int mode) {
  __shared__ float s_g[GT][DD];
  __shared__ float s_t[GT][CC];
  __shared__ float s_x[GT][CC];
  __shared__ float s_p[4][GT][CC];
  int tok0 = blockIdx.x * GT;
  int b = tok0 / LL;   // GT | LL so all 7 tokens share b
  int l0 = tok0 % LL;  // consecutive l0..l0+6
  int tid = threadIdx.x;

  // stage 1a: flattened (d,tk) loads; consecutive tids read consecutive l -> coalesced
  for (int idx = tid; idx < DD * GT; idx += 448) {
    int d = idx / GT, tk = idx % GT;
    size_t base = ((size_t)b * DD + d) * LL + l0 + tk;
    float v = ys[base] + ys[(size_t)YSTRIDE + base] +
              ys[2 * (size_t)YSTRIDE + base] + ys[3 * (size_t)YSTRIDE + base];
    s_g[tk][d] = v;
  }
  __syncthreads();

  // stage 1b: per-wave LN(192)+silu-gate; wave w = token w (7 waves exactly)
  {
    int w = tid >> 6;
    int lane = tid & 63;
    int tok = tok0 + w;
    float v0 = s_g[w][lane];
    float v1 = s_g[w][lane + 64];
    float v2 = s_g[w][lane + 128];
    float mu = wave_sum(v0 + v1 + v2) * (1.f / DD);
    float d0 = v0 - mu, d1 = v1 - mu, d2 = v2 - mu;
    float var = wave_sum(d0 * d0 + d1 * d1 + d2 * d2) * (1.f / DD);
    float rs = rsqrtf(var + 1e-6f);
    const float* zp = z + (size_t)tok * DD;
    s_g[w][lane]       = (d0 * rs * onw[lane] + onb[lane]) * silu_f(zp[lane]);
    s_g[w][lane + 64]  = (d1 * rs * onw[lane + 64] + onb[lane + 64]) * silu_f(zp[lane + 64]);
    s_g[w][lane + 128] = (d2 * rs * onw[lane + 128] + onb[lane + 128]) * silu_f(zp[lane + 128]);
  }
  __syncthreads();

  // stage 2: out_proj partials; 4 parts x 48 d; weights read once for 7 tokens
  if (tid < 4 * CC) {
    int c = tid % CC;
    int part = tid / CC;  // 0..3
    int dlo = part * 48;
    float a[GT] = {0.f, 0.f, 0.f, 0.f, 0.f, 0.f, 0.f};
#pragma unroll 8
    for (int j = 0; j < 48; j++) {
      float wv = opw[(size_t)(dlo + j) * CC + c];
#pragma unroll
      for (int tk = 0; tk < GT; tk++) a[tk] += s_g[tk][dlo + j] * wv;
    }
#pragma unroll
    for (int tk = 0; tk < GT; tk++) s_p[part][tk][c] = a[tk];
  }
  __syncthreads();
  // residual + t update
  for (int idx = tid; idx < GT * CC; idx += 448) {
    int tk = idx / CC, c = idx % CC;
    float tn = t[(size_t)(tok0 + tk) * CC + c] +
               s_p[0][tk][c] + s_p[1][tk][c] + s_p[2][tk][c] + s_p[3][tk][c];
    t[(size_t)(tok0 + tk) * CC + c] = tn;
    s_t[tk][c] = tn;
  }
  __syncthreads();

  // stage 3: LN(96) per wave with nlw/nlb (next layer's ln1, or final norm in mode 2)
  {
    int w = tid >> 6;
    int lane = tid & 63;
    float v0 = s_t[w][lane];
    float v1 = (lane < CC - 64) ? s_t[w][lane + 64] : 0.f;
    float mu2 = wave_sum(v0 + v1) * (1.f / CC);
    float d0 = v0 - mu2;
    float d1 = (lane < CC - 64) ? (v1 - mu2) : 0.f;
    float var2 = wave_sum(d0 * d0 + d1 * d1) * (1.f / CC);
    float rs2 = rsqrtf(var2 + 1e-6f);
    s_x[w][lane] = d0 * rs2 * nlw[lane] + nlb[lane];
    if (lane < CC - 64) s_x[w][lane + 64] = d1 * rs2 * nlw[lane + 64] + nlb[lane + 64];
  }
  __syncthreads();

  if (mode == 2) {
    for (int idx = tid; idx < GT * CC; idx += 448) {
      int tk = idx / CC, c = idx % CC;
      xa[(size_t)(tok0 + tk) * CC + c] = s_x[tk][c] * (1.f / LL);
    }
    return;
  }

  // stage 4: next layer's in_proj; j = tid < 384; weights read once for 7 tokens
  if (tid < 2 * DD) {
    float a[GT] = {0.f, 0.f, 0.f, 0.f, 0.f, 0.f, 0.f};
    for (int c = 0; c < CC; c++) {
      float wv = ipw[(size_t)c * (2 * DD) + tid];
#pragma unroll
      for (int tk = 0; tk < GT; tk++) a[tk] += s_x[tk][c] * wv;
    }
#pragma unroll
    for (int tk = 0; tk < GT; tk++) {
      int tok = tok0 + tk;
      if (tid < DD) xa[(size_t)tok * DD + tid] = a[tk];
      else zout[(size_t)tok * DD + (tid - DD)] = a[tk];
    }
  }
}

// ---------------- pooled head: 8 blocks x 256 thr; 2-way parallel pool + 96x43 matmul ----------------
__global__ void k_head(const float* __restrict__ t2, const float* __restrict__ hw,
                       const float* __restrict__ hb, float* __restrict__ out) {
  __shared__ float s_part[2][CC];
  __shared__ float s_pool[CC];
  int b = blockIdx.x;
  int tid = threadIdx.x;
  if (tid < 2 * CC) {
    int part = tid / CC;
    int c = tid % CC;
    int l0 = part * 98;
    float acc = 0.f;
    for (int i = 0; i < 98; i++) acc += t2[((size_t)b * LL + l0 + i) * CC + c];
    s_part[part][c] = acc;
  }
  __syncthreads();
  if (tid < CC) s_pool[tid] = s_part[0][tid] + s_part[1][tid];
  __syncthreads();
  if (tid < NCLS) {
    float acc = hb[tid];
    for (int c = 0; c < CC; c++) acc += s_pool[c] * hw[c * NCLS + tid];
    out[b * NCLS + tid] = acc;
  }
}

extern "C" void kernel_launch(void* const* d_in, const int* in_sizes, int n_in,
                              void* d_out, int out_size, void* d_ws, size_t ws_size,
                              hipStream_t stream) {
  const float* x       = (const float*)d_in[0];
  const float* patch_w = (const float*)d_in[1];
  const float* patch_b = (const float*)d_in[2];
  const float* pos     = (const float*)d_in[3];
  const float* ln1_w   = (const float*)d_in[4];
  const float* ln1_b   = (const float*)d_in[5];
  const float* ipw     = (const float*)d_in[6];
  const float* cw      = (const float*)d_in[7];
  const float* cb      = (const float*)d_in[8];
  const float* xpw     = (const float*)d_in[9];
  const float* dtw     = (const float*)d_in[10];
  const float* dtb     = (const float*)d_in[11];
  const float* alog    = (const float*)d_in[12];
  const float* dsp     = (const float*)d_in[13];
  const float* onw     = (const float*)d_in[14];
  const float* onb     = (const float*)d_in[15];
  const float* opw     = (const float*)d_in[16];
  const float* nw      = (const float*)d_in[17];
  const float* nb      = (const float*)d_in[18];
  const float* hw      = (const float*)d_in[19];
  const float* hb      = (const float*)d_in[20];
  float* out = (float*)d_out;

  // Workspace (all separate; ws_size = 256 MiB):
  float* wsf  = (float*)d_ws;
  float* t    = wsf;
  float* xa   = t    + BB * LL * CC;
  float* z    = xa   + BB * LL * DD;
  float* xcT  = z    + BB * LL * DD;
  float* dbl  = xcT  + BB * LL * DD;
  float* ysum = dbl  + BB * KDIR * DBKSZ;
  float* t2   = ysum + (size_t)KDIR * YSTRIDE;

  k_patch<<<BB * LL / PTOK, 128, 0, stream>>>(x, patch_w, patch_b, pos, t);
  k_lnproj<<<BB * LL, 384, 0, stream>>>(t, ln1_w, ln1_b, ipw, xa, z);

  for (int i = 0; i < DEPTH; i++) {
    // conv fused into x_proj; k==0 blocks emit xcT for the scan; 224 blocks
    k_xproj<<<dim3(LL / XT, KDIR, BB), 256, 0, stream>>>(
        xa, cw + i * DD * 9, cb + i * DD,
        xpw + (size_t)i * KDIR * DBLC * DD, xcT, dbl);
    // one block per (b, d-pair, k): 768 x 4 blocks
    k_scan<<<dim3(BB * DD / 2, KDIR), 256, 0, stream>>>(
        xcT, dbl, dtw + (size_t)i * KDIR * DD * RRANK, dtb + i * KDIR * DD,
        alog + (size_t)i * KDIR * DD * NSTATE, dsp + i * KDIR * DD, ysum);
    if (i < DEPTH - 1) {
      k_gateproj<<<BB * LL / GT, 448, 0, stream>>>(
          ysum, onw + i * DD, onb + i * DD, z, opw + (size_t)i * DD * CC, t,
          ln1_w + (i + 1) * CC, ln1_b + (i + 1) * CC, ipw + (size_t)(i + 1) * CC * 2 * DD,
          xa, z, 1);
    } else {
      k_gateproj<<<BB * LL / GT, 448, 0, stream>>>(
          ysum, onw + i * DD, onb + i * DD, z, opw + (size_t)i * DD * CC, t,
          nw, nb, ipw, t2, z, 2);
    }
  }

  k_head<<<BB, 256, 0, stream>>>(t2, hw, hb, out);
}